// Round 3
// baseline (1076.357 us; speedup 1.0000x reference)
//
#include <hip/hip_runtime.h>
#include <hip/hip_bf16.h>

// ---------------- constants ----------------
#define N_NODES   30000
#define F_IN      768
#define HID       128
#define NHEAD     8
#define C_OUT     4

typedef short short8_t __attribute__((ext_vector_type(8)));
typedef float float4_t __attribute__((ext_vector_type(4)));

__device__ __forceinline__ float b2f(short u) {
    union { unsigned int i; float f; } v;
    v.i = ((unsigned int)(unsigned short)u) << 16;
    return v.f;
}
__device__ __forceinline__ short f2s(float f) {
    __hip_bfloat16 h = __float2bfloat16(f);
    short s; __builtin_memcpy(&s, &h, 2); return s;
}

// ---------------- workspace layout (bytes); total ~41.5 MB ----------------
#define OFF_H_NEWS      0UL          // 30000*128 bf16
#define OFF_H_INTER     7680000UL    // 30000*128 bf16 (only first 30000 inter rows used)
#define OFF_OUT_NN      15360000UL   // 30000*128 bf16
#define OFF_OUT_IN      23040000UL   // 30000*128 bf16
#define OFF_ASRC_NN     30720000UL   // 30000*8 f32
#define OFF_ADST_NN     31680000UL
#define OFF_ASRC_IN     32640000UL
#define OFF_ADST_IN     33600000UL
#define OFF_WT_NEWS     34560000UL   // 128*768 bf16
#define OFF_WT_INTER    34756608UL
#define OFF_RS_NN       34953216UL   // 30001 int (padded)
#define OFF_RS_IN       35073280UL
#define OFF_SORT_NN     35193344UL   // 480000 int
#define OFF_SORT_IN     37113344UL   // 960000 int
#define OFF_ZERO        40953344UL   // start of zeroed region
#define OFF_DEG_NN      40953344UL
#define OFF_FILL_NN     41073408UL
#define OFF_DEG_IN      41193472UL
#define OFF_FILL_IN     41313536UL
#define OFF_SSUM        41433600UL   // 2*128 f32
#define ZERO_BYTES      481280UL     // (OFF_SSUM+1024) - OFF_ZERO
#define OFF_BETA        41434624UL   // 2 f32 (fully written by kernel)
#define OFF_FLAG        41434632UL   // 1 int (written by detect_dtype)
#define OFF_CPAR        41434640UL   // canonical bf16 small params (16-aligned)

// canonical param block element offsets
#define CP_B_NEWS  0
#define CP_B_INTER 128
#define CP_ASRC_NN 256
#define CP_ADST_NN 384
#define CP_ASRC_IN 512
#define CP_ADST_IN 640
#define CP_WK      768
#define CP_BK      17152
#define CP_Q       17280
#define CP_WOUT    17408
#define CP_BOUT    17920
#define CP_TOTAL   17924

// ---------------- dtype detector ----------------
// bf16-packed data: low 16 bits of each word are a sane N(0,1) bf16 (~100%).
// fp32 data: low 16 bits are uniform mantissa noise (~16% land in the sane
// exponent band). Threshold at 50%.
__global__ void detect_dtype(const unsigned int* __restrict__ x, int* __restrict__ flag) {
    __shared__ int cnt_s;
    if (threadIdx.x == 0) cnt_s = 0;
    __syncthreads();
    int sane = 0;
    for (int i = threadIdx.x; i < 16384; i += 256) {
        unsigned int lo = x[i] & 0xFFFFu;
        unsigned int ex = (lo >> 7) & 0xFFu;       // bf16 exponent field
        if ((ex >= 107u && ex <= 147u) || lo == 0u || lo == 0x8000u) sane++;
    }
    atomicAdd(&cnt_s, sane);
    __syncthreads();
    if (threadIdx.x == 0) *flag = (cnt_s > 8192) ? 1 : 0;   // 1 = bf16, 0 = fp32
}

// ---------------- canonicalize small params to bf16 ----------------
struct SmallParams {
    const void* src[11];
    int n[11];
    int dstoff[11];
};
__global__ void convert_small(SmallParams sp, short* __restrict__ dst,
                              const int* __restrict__ flag) {
    bool isbf = (*flag != 0);
    int idx = blockIdx.x * 256 + threadIdx.x;
    for (int s = 0; s < 11; ++s) {
        if (idx < sp.n[s]) {
            short v = isbf ? ((const short*)sp.src[s])[idx]
                           : f2s(((const float*)sp.src[s])[idx]);
            dst[sp.dstoff[s] + idx] = v;
            return;
        }
        idx -= sp.n[s];
    }
}

// ---------------- W transpose+convert: [768][128] -> [128][768] bf16 ----------------
__global__ void transpose_w(const void* __restrict__ Wraw, short* __restrict__ Wt,
                            const int* __restrict__ flag) {
    bool isbf = (*flag != 0);
    int idx = blockIdx.x * 256 + threadIdx.x;
    if (idx < F_IN * HID) {
        int n = idx / F_IN;
        int k = idx - n * F_IN;
        short v = isbf ? ((const short*)Wraw)[k * HID + n]
                       : f2s(((const float*)Wraw)[k * HID + n]);
        Wt[idx] = v;
    }
}

// ---------------- projection GEMM: H[m,:] = X[m,:768] @ W + b  (bf16 MFMA) ----------------
#define BK   32
#define LDK  40   // padded LDS leading dim

__global__ __launch_bounds__(256) void proj_gemm(
    const void* __restrict__ Xraw,  // [>=M][768] bf16 or fp32 per flag
    const short* __restrict__ Wt,   // [128][768] bf16 (canonical)
    const short* __restrict__ bias, // [128] bf16 (canonical)
    short* __restrict__ Hout,       // [M][128] bf16
    int M, const int* __restrict__ flag)
{
    __shared__ __align__(16) short As[128 * LDK];
    __shared__ __align__(16) short Bs[128 * LDK];

    const bool isbf = (*flag != 0);
    int m0   = blockIdx.x * 128;
    int tid  = threadIdx.x;
    int lane = tid & 63;
    int wid  = tid >> 6;
    int quad = lane >> 4;
    int lm   = lane & 15;

    float4_t acc[2][8];
    for (int i = 0; i < 2; ++i)
        for (int c = 0; c < 8; ++c)
            acc[i][c] = (float4_t){0.f, 0.f, 0.f, 0.f};

    int sr  = tid >> 2;        // 0..63
    int skp = (tid & 3) * 8;   // 0,8,16,24

    for (int k0 = 0; k0 < F_IN; k0 += BK) {
        __syncthreads();
        #pragma unroll
        for (int rep = 0; rep < 2; ++rep) {
            int r  = sr + rep * 64;
            int gm = m0 + r; if (gm >= M) gm = M - 1;   // clamp (stores guarded later)
            short8_t av;
            if (isbf) {
                av = *(const short8_t*)((const short*)Xraw + (size_t)gm * F_IN + k0 + skp);
            } else {
                const float* xf = (const float*)Xraw + (size_t)gm * F_IN + k0 + skp;
                float4_t f0 = *(const float4_t*)xf;
                float4_t f1 = *(const float4_t*)(xf + 4);
                av[0] = f2s(f0[0]); av[1] = f2s(f0[1]); av[2] = f2s(f0[2]); av[3] = f2s(f0[3]);
                av[4] = f2s(f1[0]); av[5] = f2s(f1[1]); av[6] = f2s(f1[2]); av[7] = f2s(f1[3]);
            }
            *(short8_t*)(&As[r * LDK + skp]) = av;
            short8_t bv = *(const short8_t*)(Wt + (size_t)r * F_IN + k0 + skp);
            *(short8_t*)(&Bs[r * LDK + skp]) = bv;
        }
        __syncthreads();

        short8_t bfrag[8];
        #pragma unroll
        for (int c = 0; c < 8; ++c)
            bfrag[c] = *(const short8_t*)(&Bs[(c * 16 + lm) * LDK + quad * 8]);
        #pragma unroll
        for (int i = 0; i < 2; ++i) {
            short8_t afrag = *(const short8_t*)(&As[(wid * 32 + i * 16 + lm) * LDK + quad * 8]);
            #pragma unroll
            for (int c = 0; c < 8; ++c)
                acc[i][c] = __builtin_amdgcn_mfma_f32_16x16x32_bf16(afrag, bfrag[c], acc[i][c], 0, 0, 0);
        }
    }

    // epilogue: C/D layout col=lane&15, row=(lane>>4)*4+reg
    #pragma unroll
    for (int i = 0; i < 2; ++i)
        #pragma unroll
        for (int c = 0; c < 8; ++c)
            #pragma unroll
            for (int r = 0; r < 4; ++r) {
                int row = wid * 32 + i * 16 + quad * 4 + r;
                int gm = m0 + row;
                if (gm < M) {
                    int col = c * 16 + lm;
                    Hout[(size_t)gm * HID + col] = f2s(acc[i][c][r] + b2f(bias[col]));
                }
            }
}

// ---------------- per-head attention dots ----------------
__global__ __launch_bounds__(128) void head_dots(
    const short* __restrict__ Hnews, const short* __restrict__ Hinter,
    const short* __restrict__ cp,
    float* __restrict__ asrc_nn, float* __restrict__ adst_nn,
    float* __restrict__ asrc_in, float* __restrict__ adst_in)
{
    int n = blockIdx.x, tid = threadIdx.x;
    int h = tid >> 4, d = tid & 15;
    float hv  = b2f(Hnews[(size_t)n * HID + tid]);
    float hv2 = b2f(Hinter[(size_t)n * HID + tid]);
    float v0 = hv  * b2f(cp[CP_ASRC_NN + tid]);
    float v1 = hv  * b2f(cp[CP_ADST_NN + tid]);
    float v2 = hv2 * b2f(cp[CP_ASRC_IN + tid]);
    float v3 = hv  * b2f(cp[CP_ADST_IN + tid]);
    #pragma unroll
    for (int off = 8; off; off >>= 1) {
        v0 += __shfl_down(v0, off, 16);
        v1 += __shfl_down(v1, off, 16);
        v2 += __shfl_down(v2, off, 16);
        v3 += __shfl_down(v3, off, 16);
    }
    if (d == 0) {
        asrc_nn[n * NHEAD + h] = v0;
        adst_nn[n * NHEAD + h] = v1;
        asrc_in[n * NHEAD + h] = v2;
        adst_in[n * NHEAD + h] = v3;
    }
}

// ---------------- CSR build ----------------
__global__ void count_deg(const int* __restrict__ dst, int E, int* __restrict__ deg) {
    int i = blockIdx.x * 256 + threadIdx.x;
    if (i < E) {
        int d = dst[i];
        if (d >= 0 && d < N_NODES) atomicAdd(&deg[d], 1);
    }
}

__global__ __launch_bounds__(256) void prefix_scan_simple(
    const int* __restrict__ deg, int* __restrict__ row_start, int n)
{
    __shared__ int psum[256];
    int tid = threadIdx.x;
    int chunk = (n + 255) / 256;
    int lo = tid * chunk;
    int hi = lo + chunk; if (hi > n) hi = n; if (lo > n) lo = n;
    int s = 0;
    for (int i = lo; i < hi; ++i) s += deg[i];
    psum[tid] = s;
    __syncthreads();
    for (int off = 1; off < 256; off <<= 1) {
        int v = (tid >= off) ? psum[tid - off] : 0;
        __syncthreads();
        psum[tid] += v;
        __syncthreads();
    }
    int base = tid ? psum[tid - 1] : 0;   // exclusive prefix of this chunk
    for (int i = lo; i < hi; ++i) { row_start[i] = base; base += deg[i]; }
    if (tid == 255) row_start[n] = psum[255];
}

__global__ void scatter_edges(const int* __restrict__ src, const int* __restrict__ dst, int E,
                              const int* __restrict__ row_start, int* __restrict__ fill,
                              int* __restrict__ sorted_src) {
    int i = blockIdx.x * 256 + threadIdx.x;
    if (i < E) {
        int d = dst[i];
        if (d >= 0 && d < N_NODES) {
            int pos = row_start[d] + atomicAdd(&fill[d], 1);
            if (pos >= 0 && pos < E) sorted_src[pos] = src[i];
        }
    }
}

// ---------------- fused edge-softmax + aggregation (single pass; e is O(10),
// clamped to [-80,80] so exp can't overflow fp32) ----------------
__global__ __launch_bounds__(128) void aggregate(
    const short* __restrict__ Hsrc, const float* __restrict__ asrc, const float* __restrict__ adst,
    const int* __restrict__ row_start, const int* __restrict__ sorted_src,
    short* __restrict__ outbuf)
{
    int dn  = blockIdx.x;
    int tid = threadIdx.x;
    int head = tid >> 4;
    int start = row_start[dn], end = row_start[dn + 1];
    float adv = adst[dn * NHEAD + head];

    float den = 0.f, acc = 0.f;
    for (int j = start; j < end; ++j) {
        int s = sorted_src[j];
        s = (s < 0) ? 0 : (s >= N_NODES ? N_NODES - 1 : s);   // containment
        float e = asrc[s * NHEAD + head] + adv;
        e = (e < 0.f) ? 0.2f * e : e;
        e = fminf(fmaxf(e, -80.f), 80.f);
        float ex = __expf(e);
        den += ex;
        acc += ex * b2f(Hsrc[(size_t)s * HID + tid]);
    }
    float o = acc / (den + 1e-16f);
    outbuf[(size_t)dn * HID + tid] = f2s(fmaxf(o, 0.f));
}

// ---------------- semantic score: Ssum[p][j] += sum_n tanh(out_p[n] @ Wk + bk)[j] ----------------
__global__ __launch_bounds__(128) void score_kernel(
    const short* __restrict__ out_nn, const short* __restrict__ out_in,
    const short* __restrict__ cp,
    float* __restrict__ Ssum)
{
    __shared__ __align__(16) short wk_s[HID * HID];
    __shared__ float row_s[HID];
    int tid = threadIdx.x;
    const short* src = (blockIdx.y == 0) ? out_nn : out_in;

    for (int i = tid * 8; i < HID * HID; i += 128 * 8)
        *(short8_t*)(&wk_s[i]) = *(const short8_t*)(cp + CP_WK + i);
    __syncthreads();

    float bkj = b2f(cp[CP_BK + tid]);
    float lsum = 0.f;
    for (int nn = 0; nn < 128; ++nn) {
        int node = blockIdx.x * 128 + nn;
        if (node >= N_NODES) break;          // uniform across block
        __syncthreads();
        row_s[tid] = b2f(src[(size_t)node * HID + tid]);
        __syncthreads();
        float a = bkj;
        #pragma unroll 8
        for (int k = 0; k < HID; ++k)
            a += row_s[k] * b2f(wk_s[k * HID + tid]);
        lsum += tanhf(a);
    }
    atomicAdd(&Ssum[blockIdx.y * HID + tid], lsum);
}

// ---------------- beta (softmax over 2 metapath scores) ----------------
__global__ __launch_bounds__(64) void beta_kernel(
    const float* __restrict__ Ssum, const short* __restrict__ cp, float* __restrict__ beta)
{
    int lane = threadIdx.x;
    float q0 = b2f(cp[CP_Q + lane]), q1 = b2f(cp[CP_Q + lane + 64]);
    float s0 = q0 * Ssum[lane] + q1 * Ssum[lane + 64];
    float s1 = q0 * Ssum[128 + lane] + q1 * Ssum[192 + lane];
    #pragma unroll
    for (int off = 32; off; off >>= 1) {
        s0 += __shfl_down(s0, off, 64);
        s1 += __shfl_down(s1, off, 64);
    }
    if (lane == 0) {
        float sc0 = s0 / (float)N_NODES;
        float sc1 = s1 / (float)N_NODES;
        float mx = fmaxf(sc0, sc1);
        float e0 = __expf(sc0 - mx), e1 = __expf(sc1 - mx);
        float inv = 1.f / (e0 + e1);
        beta[0] = e0 * inv;
        beta[1] = e1 * inv;
    }
}

// ---------------- final: elu(beta0*out_nn + beta1*out_in) @ W_out + b_out ----------------
__global__ __launch_bounds__(128) void final_out(
    const short* __restrict__ out_nn, const short* __restrict__ out_in,
    const float* __restrict__ beta, const short* __restrict__ cp,
    void* __restrict__ Yraw, const int* __restrict__ flag)
{
    __shared__ float partial[2][C_OUT];
    bool isbf = (*flag != 0);
    int n = blockIdx.x, tid = threadIdx.x, lane = tid & 63, w = tid >> 6;
    float b0 = beta[0], b1 = beta[1];
    float f = b0 * b2f(out_nn[(size_t)n * HID + tid]) + b1 * b2f(out_in[(size_t)n * HID + tid]);
    float e = (f > 0.f) ? f : expm1f(f);
    float p[C_OUT];
    #pragma unroll
    for (int c = 0; c < C_OUT; ++c) p[c] = e * b2f(cp[CP_WOUT + tid * C_OUT + c]);
    #pragma unroll
    for (int off = 32; off; off >>= 1)
        #pragma unroll
        for (int c = 0; c < C_OUT; ++c) p[c] += __shfl_down(p[c], off, 64);
    if (lane == 0)
        #pragma unroll
        for (int c = 0; c < C_OUT; ++c) partial[w][c] = p[c];
    __syncthreads();
    if (tid < C_OUT) {
        float r = partial[0][tid] + partial[1][tid] + b2f(cp[CP_BOUT + tid]);
        if (isbf) ((__hip_bfloat16*)Yraw)[n * C_OUT + tid] = __float2bfloat16(r);
        else      ((float*)Yraw)[n * C_OUT + tid] = r;
    }
}

// ---------------- launch ----------------
extern "C" void kernel_launch(void* const* d_in, const int* in_sizes, int n_in,
                              void* d_out, int out_size, void* d_ws, size_t ws_size,
                              hipStream_t stream) {
    const void* x_news  = d_in[0];
    const void* x_inter = d_in[1];
    const int*  edge_nn = (const int*)d_in[2];
    const int*  edge_in = (const int*)d_in[3];

    int E_nn = in_sizes[2] / 2;
    int E_in = in_sizes[3] / 2;

    char* ws = (char*)d_ws;
    short* h_news  = (short*)(ws + OFF_H_NEWS);
    short* h_inter = (short*)(ws + OFF_H_INTER);
    short* out_nn  = (short*)(ws + OFF_OUT_NN);
    short* out_in  = (short*)(ws + OFF_OUT_IN);
    float* asrc_nn = (float*)(ws + OFF_ASRC_NN);
    float* adst_nn = (float*)(ws + OFF_ADST_NN);
    float* asrc_in = (float*)(ws + OFF_ASRC_IN);
    float* adst_in = (float*)(ws + OFF_ADST_IN);
    short* wt_news  = (short*)(ws + OFF_WT_NEWS);
    short* wt_inter = (short*)(ws + OFF_WT_INTER);
    int* rs_nn   = (int*)(ws + OFF_RS_NN);
    int* rs_in   = (int*)(ws + OFF_RS_IN);
    int* sort_nn = (int*)(ws + OFF_SORT_NN);
    int* sort_in = (int*)(ws + OFF_SORT_IN);
    int* deg_nn  = (int*)(ws + OFF_DEG_NN);
    int* fill_nn = (int*)(ws + OFF_FILL_NN);
    int* deg_in  = (int*)(ws + OFF_DEG_IN);
    int* fill_in = (int*)(ws + OFF_FILL_IN);
    float* Ssum  = (float*)(ws + OFF_SSUM);
    float* beta  = (float*)(ws + OFF_BETA);
    int*   flag  = (int*)(ws + OFF_FLAG);
    short* cp    = (short*)(ws + OFF_CPAR);

    hipMemsetAsync(ws + OFF_ZERO, 0, ZERO_BYTES, stream);

    detect_dtype<<<1, 256, 0, stream>>>((const unsigned int*)x_news, flag);

    SmallParams sp;
    const int srcidx[11] = {5, 7, 8, 9, 10, 11, 12, 13, 14, 15, 16};
    const int ns[11]     = {128, 128, 128, 128, 128, 128, 16384, 128, 128, 512, 4};
    const int doff[11]   = {CP_B_NEWS, CP_B_INTER, CP_ASRC_NN, CP_ADST_NN, CP_ASRC_IN,
                            CP_ADST_IN, CP_WK, CP_BK, CP_Q, CP_WOUT, CP_BOUT};
    for (int i = 0; i < 11; ++i) { sp.src[i] = d_in[srcidx[i]]; sp.n[i] = ns[i]; sp.dstoff[i] = doff[i]; }
    convert_small<<<(CP_TOTAL + 255) / 256, 256, 0, stream>>>(sp, cp, flag);

    transpose_w<<<(F_IN * HID + 255) / 256, 256, 0, stream>>>(d_in[4], wt_news, flag);
    transpose_w<<<(F_IN * HID + 255) / 256, 256, 0, stream>>>(d_in[6], wt_inter, flag);

    int gblocks = (N_NODES + 127) / 128;
    proj_gemm<<<gblocks, 256, 0, stream>>>(x_news, wt_news, cp + CP_B_NEWS, h_news, N_NODES, flag);
    proj_gemm<<<gblocks, 256, 0, stream>>>(x_inter, wt_inter, cp + CP_B_INTER, h_inter, N_NODES, flag);

    head_dots<<<N_NODES, 128, 0, stream>>>(h_news, h_inter, cp,
        asrc_nn, adst_nn, asrc_in, adst_in);

    count_deg<<<(E_nn + 255) / 256, 256, 0, stream>>>(edge_nn + E_nn, E_nn, deg_nn);
    count_deg<<<(E_in + 255) / 256, 256, 0, stream>>>(edge_in + E_in, E_in, deg_in);

    prefix_scan_simple<<<1, 256, 0, stream>>>(deg_nn, rs_nn, N_NODES);
    prefix_scan_simple<<<1, 256, 0, stream>>>(deg_in, rs_in, N_NODES);

    scatter_edges<<<(E_nn + 255) / 256, 256, 0, stream>>>(edge_nn, edge_nn + E_nn, E_nn, rs_nn, fill_nn, sort_nn);
    scatter_edges<<<(E_in + 255) / 256, 256, 0, stream>>>(edge_in, edge_in + E_in, E_in, rs_in, fill_in, sort_in);

    aggregate<<<N_NODES, 128, 0, stream>>>(h_news, asrc_nn, adst_nn, rs_nn, sort_nn, out_nn);
    aggregate<<<N_NODES, 128, 0, stream>>>(h_inter, asrc_in, adst_in, rs_in, sort_in, out_in);

    score_kernel<<<dim3((N_NODES + 127) / 128, 2), 128, 0, stream>>>(out_nn, out_in, cp, Ssum);
    beta_kernel<<<1, 64, 0, stream>>>(Ssum, cp, beta);

    final_out<<<N_NODES, 128, 0, stream>>>(out_nn, out_in, beta, cp, d_out, flag);
}

// Round 4
// 874.282 us; speedup vs baseline: 1.2311x; 1.2311x over previous
//
#include <hip/hip_runtime.h>
#include <hip/hip_bf16.h>

// ---------------- constants ----------------
#define N_NODES   30000
#define F_IN      768
#define HID       128
#define NHEAD     8
#define C_OUT     4

typedef short short8_t __attribute__((ext_vector_type(8)));
typedef float float4_t __attribute__((ext_vector_type(4)));

__device__ __forceinline__ float b2f(short u) {
    union { unsigned int i; float f; } v;
    v.i = ((unsigned int)(unsigned short)u) << 16;
    return v.f;
}
__device__ __forceinline__ short f2s(float f) {
    __hip_bfloat16 h = __float2bfloat16(f);
    short s; __builtin_memcpy(&s, &h, 2); return s;
}

// ---------------- workspace layout (bytes); total ~41.6 MB ----------------
#define OFF_H_NEWS      0UL          // 30000*128 bf16
#define OFF_H_INTER     7680000UL    // 30000*128 bf16 (only first 30000 inter rows used)
#define OFF_OUT_NN      15360000UL   // 30000*128 bf16
#define OFF_OUT_IN      23040000UL   // 30000*128 bf16
#define OFF_ASRC_NN     30720000UL   // 30000*8 f32
#define OFF_ADST_NN     31680000UL
#define OFF_ASRC_IN     32640000UL
#define OFF_ADST_IN     33600000UL
#define OFF_WT_NEWS     34560000UL   // 128*768 bf16
#define OFF_WT_INTER    34756608UL
#define OFF_RS_NN       34953216UL   // 30001 int (padded)
#define OFF_RS_IN       35073280UL
#define OFF_SORT_NN     35193344UL   // 480000 int
#define OFF_SORT_IN     37113344UL   // 960000 int
#define OFF_ZERO        40953344UL   // start of zeroed region
#define OFF_DEG_NN      40953344UL
#define OFF_FILL_NN     41073408UL
#define OFF_DEG_IN      41193472UL
#define OFF_FILL_IN     41313536UL
#define OFF_SSUM        41433600UL   // 2*128 f32
#define ZERO_BYTES      481280UL     // (OFF_SSUM+1024) - OFF_ZERO
#define OFF_BETA        41434624UL   // 2 f32 (fully written by kernel)
#define OFF_FLAG        41434632UL   // 1 int (written by detect_dtype)
#define OFF_CPAR        41434640UL   // canonical bf16 small params
#define OFF_WKT         41470496UL   // 128*128 bf16, Wk transposed (j-major)

// canonical param block element offsets
#define CP_B_NEWS  0
#define CP_B_INTER 128
#define CP_ASRC_NN 256
#define CP_ADST_NN 384
#define CP_ASRC_IN 512
#define CP_ADST_IN 640
#define CP_WK      768
#define CP_BK      17152
#define CP_Q       17280
#define CP_WOUT    17408
#define CP_BOUT    17920
#define CP_TOTAL   17924

// ---------------- dtype detector ----------------
__global__ void detect_dtype(const unsigned int* __restrict__ x, int* __restrict__ flag) {
    __shared__ int cnt_s;
    if (threadIdx.x == 0) cnt_s = 0;
    __syncthreads();
    int sane = 0;
    for (int i = threadIdx.x; i < 16384; i += 256) {
        unsigned int lo = x[i] & 0xFFFFu;
        unsigned int ex = (lo >> 7) & 0xFFu;       // bf16 exponent field
        if ((ex >= 107u && ex <= 147u) || lo == 0u || lo == 0x8000u) sane++;
    }
    atomicAdd(&cnt_s, sane);
    __syncthreads();
    if (threadIdx.x == 0) *flag = (cnt_s > 8192) ? 1 : 0;   // 1 = bf16, 0 = fp32
}

// ---------------- canonicalize small params to bf16 ----------------
struct SmallParams {
    const void* src[11];
    int n[11];
    int dstoff[11];
};
__global__ void convert_small(SmallParams sp, short* __restrict__ dst,
                              const int* __restrict__ flag) {
    bool isbf = (*flag != 0);
    int idx = blockIdx.x * 256 + threadIdx.x;
    for (int s = 0; s < 11; ++s) {
        if (idx < sp.n[s]) {
            short v = isbf ? ((const short*)sp.src[s])[idx]
                           : f2s(((const float*)sp.src[s])[idx]);
            dst[sp.dstoff[s] + idx] = v;
            return;
        }
        idx -= sp.n[s];
    }
}

// ---------------- W transpose+convert: [768][128] -> [128][768] bf16 ----------------
__global__ void transpose_w(const void* __restrict__ Wraw, short* __restrict__ Wt,
                            const int* __restrict__ flag) {
    bool isbf = (*flag != 0);
    int idx = blockIdx.x * 256 + threadIdx.x;
    if (idx < F_IN * HID) {
        int n = idx / F_IN;
        int k = idx - n * F_IN;
        short v = isbf ? ((const short*)Wraw)[k * HID + n]
                       : f2s(((const float*)Wraw)[k * HID + n]);
        Wt[idx] = v;
    }
}

// ---------------- Wk transpose (canonical bf16 -> wkT[j][k]) ----------------
__global__ void transpose_wk(const short* __restrict__ cp, short* __restrict__ wkT) {
    int idx = blockIdx.x * 256 + threadIdx.x;
    if (idx < HID * HID) {
        int j = idx >> 7;
        int k = idx & 127;
        wkT[idx] = cp[CP_WK + k * HID + j];
    }
}

// ---------------- projection GEMM: H[m,:] = X[m,:768] @ W + b  (bf16 MFMA) ----------------
#define BK   32
#define LDK  40   // padded LDS leading dim

__global__ __launch_bounds__(256) void proj_gemm(
    const void* __restrict__ Xraw,  // [>=M][768] bf16 or fp32 per flag
    const short* __restrict__ Wt,   // [128][768] bf16 (canonical)
    const short* __restrict__ bias, // [128] bf16 (canonical)
    short* __restrict__ Hout,       // [M][128] bf16
    int M, const int* __restrict__ flag)
{
    __shared__ __align__(16) short As[128 * LDK];
    __shared__ __align__(16) short Bs[128 * LDK];

    const bool isbf = (*flag != 0);
    int m0   = blockIdx.x * 128;
    int tid  = threadIdx.x;
    int lane = tid & 63;
    int wid  = tid >> 6;
    int quad = lane >> 4;
    int lm   = lane & 15;

    float4_t acc[2][8];
    for (int i = 0; i < 2; ++i)
        for (int c = 0; c < 8; ++c)
            acc[i][c] = (float4_t){0.f, 0.f, 0.f, 0.f};

    int sr  = tid >> 2;        // 0..63
    int skp = (tid & 3) * 8;   // 0,8,16,24

    for (int k0 = 0; k0 < F_IN; k0 += BK) {
        __syncthreads();
        #pragma unroll
        for (int rep = 0; rep < 2; ++rep) {
            int r  = sr + rep * 64;
            int gm = m0 + r; if (gm >= M) gm = M - 1;   // clamp (stores guarded later)
            short8_t av;
            if (isbf) {
                av = *(const short8_t*)((const short*)Xraw + (size_t)gm * F_IN + k0 + skp);
            } else {
                const float* xf = (const float*)Xraw + (size_t)gm * F_IN + k0 + skp;
                float4_t f0 = *(const float4_t*)xf;
                float4_t f1 = *(const float4_t*)(xf + 4);
                av[0] = f2s(f0[0]); av[1] = f2s(f0[1]); av[2] = f2s(f0[2]); av[3] = f2s(f0[3]);
                av[4] = f2s(f1[0]); av[5] = f2s(f1[1]); av[6] = f2s(f1[2]); av[7] = f2s(f1[3]);
            }
            *(short8_t*)(&As[r * LDK + skp]) = av;
            short8_t bv = *(const short8_t*)(Wt + (size_t)r * F_IN + k0 + skp);
            *(short8_t*)(&Bs[r * LDK + skp]) = bv;
        }
        __syncthreads();

        short8_t bfrag[8];
        #pragma unroll
        for (int c = 0; c < 8; ++c)
            bfrag[c] = *(const short8_t*)(&Bs[(c * 16 + lm) * LDK + quad * 8]);
        #pragma unroll
        for (int i = 0; i < 2; ++i) {
            short8_t afrag = *(const short8_t*)(&As[(wid * 32 + i * 16 + lm) * LDK + quad * 8]);
            #pragma unroll
            for (int c = 0; c < 8; ++c)
                acc[i][c] = __builtin_amdgcn_mfma_f32_16x16x32_bf16(afrag, bfrag[c], acc[i][c], 0, 0, 0);
        }
    }

    // epilogue: C/D layout col=lane&15, row=(lane>>4)*4+reg
    #pragma unroll
    for (int i = 0; i < 2; ++i)
        #pragma unroll
        for (int c = 0; c < 8; ++c)
            #pragma unroll
            for (int r = 0; r < 4; ++r) {
                int row = wid * 32 + i * 16 + quad * 4 + r;
                int gm = m0 + row;
                if (gm < M) {
                    int col = c * 16 + lm;
                    Hout[(size_t)gm * HID + col] = f2s(acc[i][c][r] + b2f(bias[col]));
                }
            }
}

// ---------------- per-head attention dots ----------------
__global__ __launch_bounds__(128) void head_dots(
    const short* __restrict__ Hnews, const short* __restrict__ Hinter,
    const short* __restrict__ cp,
    float* __restrict__ asrc_nn, float* __restrict__ adst_nn,
    float* __restrict__ asrc_in, float* __restrict__ adst_in)
{
    int n = blockIdx.x, tid = threadIdx.x;
    int h = tid >> 4, d = tid & 15;
    float hv  = b2f(Hnews[(size_t)n * HID + tid]);
    float hv2 = b2f(Hinter[(size_t)n * HID + tid]);
    float v0 = hv  * b2f(cp[CP_ASRC_NN + tid]);
    float v1 = hv  * b2f(cp[CP_ADST_NN + tid]);
    float v2 = hv2 * b2f(cp[CP_ASRC_IN + tid]);
    float v3 = hv  * b2f(cp[CP_ADST_IN + tid]);
    #pragma unroll
    for (int off = 8; off; off >>= 1) {
        v0 += __shfl_down(v0, off, 16);
        v1 += __shfl_down(v1, off, 16);
        v2 += __shfl_down(v2, off, 16);
        v3 += __shfl_down(v3, off, 16);
    }
    if (d == 0) {
        asrc_nn[n * NHEAD + h] = v0;
        adst_nn[n * NHEAD + h] = v1;
        asrc_in[n * NHEAD + h] = v2;
        adst_in[n * NHEAD + h] = v3;
    }
}

// ---------------- CSR build ----------------
__global__ void count_deg(const int* __restrict__ dst, int E, int* __restrict__ deg) {
    int i = blockIdx.x * 256 + threadIdx.x;
    if (i < E) {
        int d = dst[i];
        if (d >= 0 && d < N_NODES) atomicAdd(&deg[d], 1);
    }
}

__global__ __launch_bounds__(256) void prefix_scan_simple(
    const int* __restrict__ deg, int* __restrict__ row_start, int n)
{
    __shared__ int psum[256];
    int tid = threadIdx.x;
    int chunk = (n + 255) / 256;
    int lo = tid * chunk;
    int hi = lo + chunk; if (hi > n) hi = n; if (lo > n) lo = n;
    int s = 0;
    for (int i = lo; i < hi; ++i) s += deg[i];
    psum[tid] = s;
    __syncthreads();
    for (int off = 1; off < 256; off <<= 1) {
        int v = (tid >= off) ? psum[tid - off] : 0;
        __syncthreads();
        psum[tid] += v;
        __syncthreads();
    }
    int base = tid ? psum[tid - 1] : 0;   // exclusive prefix of this chunk
    for (int i = lo; i < hi; ++i) { row_start[i] = base; base += deg[i]; }
    if (tid == 255) row_start[n] = psum[255];
}

__global__ void scatter_edges(const int* __restrict__ src, const int* __restrict__ dst, int E,
                              const int* __restrict__ row_start, int* __restrict__ fill,
                              int* __restrict__ sorted_src) {
    int i = blockIdx.x * 256 + threadIdx.x;
    if (i < E) {
        int d = dst[i];
        if (d >= 0 && d < N_NODES) {
            int pos = row_start[d] + atomicAdd(&fill[d], 1);
            if (pos >= 0 && pos < E) sorted_src[pos] = src[i];
        }
    }
}

// ---------------- fused edge-softmax + aggregation (single pass) ----------------
__global__ __launch_bounds__(128) void aggregate(
    const short* __restrict__ Hsrc, const float* __restrict__ asrc, const float* __restrict__ adst,
    const int* __restrict__ row_start, const int* __restrict__ sorted_src,
    short* __restrict__ outbuf)
{
    int dn  = blockIdx.x;
    int tid = threadIdx.x;
    int head = tid >> 4;
    int start = row_start[dn], end = row_start[dn + 1];
    float adv = adst[dn * NHEAD + head];

    float den = 0.f, acc = 0.f;
    for (int j = start; j < end; ++j) {
        int s = sorted_src[j];
        s = (s < 0) ? 0 : (s >= N_NODES ? N_NODES - 1 : s);   // containment
        float e = asrc[s * NHEAD + head] + adv;
        e = (e < 0.f) ? 0.2f * e : e;
        e = fminf(fmaxf(e, -80.f), 80.f);
        float ex = __expf(e);
        den += ex;
        acc += ex * b2f(Hsrc[(size_t)s * HID + tid]);
    }
    float o = acc / (den + 1e-16f);
    outbuf[(size_t)dn * HID + tid] = f2s(fmaxf(o, 0.f));
}

// ---------------- semantic score via MFMA:
// Ssum[p][j] += sum_n tanh( (out_p @ Wk)[n][j] + bk[j] )
// A-frags direct from out_p (each row read once -> no LDS); B-frags direct from wkT.
__global__ __launch_bounds__(256) void score_mfma(
    const short* __restrict__ out_nn, const short* __restrict__ out_in,
    const short* __restrict__ wkT, const short* __restrict__ cp,
    float* __restrict__ Ssum)
{
    __shared__ float col_s[HID];
    int tid  = threadIdx.x;
    int lane = tid & 63;
    int wid  = tid >> 6;
    int quad = lane >> 4;
    int lm   = lane & 15;
    const short* src = blockIdx.y ? out_in : out_nn;
    int m0 = blockIdx.x * 128;

    if (tid < HID) col_s[tid] = 0.f;
    __syncthreads();

    float4_t acc[2][8];
    #pragma unroll
    for (int i = 0; i < 2; ++i)
        #pragma unroll
        for (int c = 0; c < 8; ++c)
            acc[i][c] = (float4_t){0.f, 0.f, 0.f, 0.f};

    #pragma unroll
    for (int kc = 0; kc < 4; ++kc) {
        short8_t bfrag[8];
        #pragma unroll
        for (int c = 0; c < 8; ++c)
            bfrag[c] = *(const short8_t*)(wkT + (c * 16 + lm) * HID + kc * 32 + quad * 8);
        #pragma unroll
        for (int i = 0; i < 2; ++i) {
            int gm = m0 + wid * 32 + i * 16 + lm;
            if (gm >= N_NODES) gm = N_NODES - 1;      // clamp; epilogue guards
            short8_t afrag = *(const short8_t*)(src + (size_t)gm * HID + kc * 32 + quad * 8);
            #pragma unroll
            for (int c = 0; c < 8; ++c)
                acc[i][c] = __builtin_amdgcn_mfma_f32_16x16x32_bf16(afrag, bfrag[c], acc[i][c], 0, 0, 0);
        }
    }

    // epilogue: tanh + row-sum.  C/D layout: col=c*16+lm, row=wid*32+i*16+quad*4+r
    #pragma unroll
    for (int c = 0; c < 8; ++c) {
        int col = c * 16 + lm;
        float bkc = b2f(cp[CP_BK + col]);
        float lsum = 0.f;
        #pragma unroll
        for (int i = 0; i < 2; ++i)
            #pragma unroll
            for (int r = 0; r < 4; ++r) {
                int node = m0 + wid * 32 + i * 16 + quad * 4 + r;
                if (node < N_NODES) {
                    float a = acc[i][c][r] + bkc;
                    a = fminf(fmaxf(a, -15.f), 15.f);
                    float t = __expf(2.f * a);
                    lsum += (t - 1.f) / (t + 1.f);
                }
            }
        float v = lsum;
        v += __shfl_down(v, 32, 64);
        v += __shfl_down(v, 16, 64);
        if (quad == 0) atomicAdd(&col_s[col], v);
    }
    __syncthreads();
    if (tid < HID) atomicAdd(&Ssum[blockIdx.y * HID + tid], col_s[tid]);
}

// ---------------- beta (softmax over 2 metapath scores) ----------------
__global__ __launch_bounds__(64) void beta_kernel(
    const float* __restrict__ Ssum, const short* __restrict__ cp, float* __restrict__ beta)
{
    int lane = threadIdx.x;
    float q0 = b2f(cp[CP_Q + lane]), q1 = b2f(cp[CP_Q + lane + 64]);
    float s0 = q0 * Ssum[lane] + q1 * Ssum[lane + 64];
    float s1 = q0 * Ssum[128 + lane] + q1 * Ssum[192 + lane];
    #pragma unroll
    for (int off = 32; off; off >>= 1) {
        s0 += __shfl_down(s0, off, 64);
        s1 += __shfl_down(s1, off, 64);
    }
    if (lane == 0) {
        float sc0 = s0 / (float)N_NODES;
        float sc1 = s1 / (float)N_NODES;
        float mx = fmaxf(sc0, sc1);
        float e0 = __expf(sc0 - mx), e1 = __expf(sc1 - mx);
        float inv = 1.f / (e0 + e1);
        beta[0] = e0 * inv;
        beta[1] = e1 * inv;
    }
}

// ---------------- final: elu(beta0*out_nn + beta1*out_in) @ W_out + b_out ----------------
__global__ __launch_bounds__(128) void final_out(
    const short* __restrict__ out_nn, const short* __restrict__ out_in,
    const float* __restrict__ beta, const short* __restrict__ cp,
    void* __restrict__ Yraw, const int* __restrict__ flag)
{
    __shared__ float partial[2][C_OUT];
    bool isbf = (*flag != 0);
    int n = blockIdx.x, tid = threadIdx.x, lane = tid & 63, w = tid >> 6;
    float b0 = beta[0], b1 = beta[1];
    float f = b0 * b2f(out_nn[(size_t)n * HID + tid]) + b1 * b2f(out_in[(size_t)n * HID + tid]);
    float e = (f > 0.f) ? f : expm1f(f);
    float p[C_OUT];
    #pragma unroll
    for (int c = 0; c < C_OUT; ++c) p[c] = e * b2f(cp[CP_WOUT + tid * C_OUT + c]);
    #pragma unroll
    for (int off = 32; off; off >>= 1)
        #pragma unroll
        for (int c = 0; c < C_OUT; ++c) p[c] += __shfl_down(p[c], off, 64);
    if (lane == 0)
        #pragma unroll
        for (int c = 0; c < C_OUT; ++c) partial[w][c] = p[c];
    __syncthreads();
    if (tid < C_OUT) {
        float r = partial[0][tid] + partial[1][tid] + b2f(cp[CP_BOUT + tid]);
        if (isbf) ((__hip_bfloat16*)Yraw)[n * C_OUT + tid] = __float2bfloat16(r);
        else      ((float*)Yraw)[n * C_OUT + tid] = r;
    }
}

// ---------------- launch ----------------
extern "C" void kernel_launch(void* const* d_in, const int* in_sizes, int n_in,
                              void* d_out, int out_size, void* d_ws, size_t ws_size,
                              hipStream_t stream) {
    const void* x_news  = d_in[0];
    const void* x_inter = d_in[1];
    const int*  edge_nn = (const int*)d_in[2];
    const int*  edge_in = (const int*)d_in[3];

    int E_nn = in_sizes[2] / 2;
    int E_in = in_sizes[3] / 2;

    char* ws = (char*)d_ws;
    short* h_news  = (short*)(ws + OFF_H_NEWS);
    short* h_inter = (short*)(ws + OFF_H_INTER);
    short* out_nn  = (short*)(ws + OFF_OUT_NN);
    short* out_in  = (short*)(ws + OFF_OUT_IN);
    float* asrc_nn = (float*)(ws + OFF_ASRC_NN);
    float* adst_nn = (float*)(ws + OFF_ADST_NN);
    float* asrc_in = (float*)(ws + OFF_ASRC_IN);
    float* adst_in = (float*)(ws + OFF_ADST_IN);
    short* wt_news  = (short*)(ws + OFF_WT_NEWS);
    short* wt_inter = (short*)(ws + OFF_WT_INTER);
    int* rs_nn   = (int*)(ws + OFF_RS_NN);
    int* rs_in   = (int*)(ws + OFF_RS_IN);
    int* sort_nn = (int*)(ws + OFF_SORT_NN);
    int* sort_in = (int*)(ws + OFF_SORT_IN);
    int* deg_nn  = (int*)(ws + OFF_DEG_NN);
    int* fill_nn = (int*)(ws + OFF_FILL_NN);
    int* deg_in  = (int*)(ws + OFF_DEG_IN);
    int* fill_in = (int*)(ws + OFF_FILL_IN);
    float* Ssum  = (float*)(ws + OFF_SSUM);
    float* beta  = (float*)(ws + OFF_BETA);
    int*   flag  = (int*)(ws + OFF_FLAG);
    short* cp    = (short*)(ws + OFF_CPAR);
    short* wkT   = (short*)(ws + OFF_WKT);

    hipMemsetAsync(ws + OFF_ZERO, 0, ZERO_BYTES, stream);

    detect_dtype<<<1, 256, 0, stream>>>((const unsigned int*)x_news, flag);

    SmallParams sp;
    const int srcidx[11] = {5, 7, 8, 9, 10, 11, 12, 13, 14, 15, 16};
    const int ns[11]     = {128, 128, 128, 128, 128, 128, 16384, 128, 128, 512, 4};
    const int doff[11]   = {CP_B_NEWS, CP_B_INTER, CP_ASRC_NN, CP_ADST_NN, CP_ASRC_IN,
                            CP_ADST_IN, CP_WK, CP_BK, CP_Q, CP_WOUT, CP_BOUT};
    for (int i = 0; i < 11; ++i) { sp.src[i] = d_in[srcidx[i]]; sp.n[i] = ns[i]; sp.dstoff[i] = doff[i]; }
    convert_small<<<(CP_TOTAL + 255) / 256, 256, 0, stream>>>(sp, cp, flag);

    transpose_wk<<<(HID * HID + 255) / 256, 256, 0, stream>>>(cp, wkT);

    transpose_w<<<(F_IN * HID + 255) / 256, 256, 0, stream>>>(d_in[4], wt_news, flag);
    transpose_w<<<(F_IN * HID + 255) / 256, 256, 0, stream>>>(d_in[6], wt_inter, flag);

    int gblocks = (N_NODES + 127) / 128;
    proj_gemm<<<gblocks, 256, 0, stream>>>(x_news, wt_news, cp + CP_B_NEWS, h_news, N_NODES, flag);
    proj_gemm<<<gblocks, 256, 0, stream>>>(x_inter, wt_inter, cp + CP_B_INTER, h_inter, N_NODES, flag);

    head_dots<<<N_NODES, 128, 0, stream>>>(h_news, h_inter, cp,
        asrc_nn, adst_nn, asrc_in, adst_in);

    count_deg<<<(E_nn + 255) / 256, 256, 0, stream>>>(edge_nn + E_nn, E_nn, deg_nn);
    count_deg<<<(E_in + 255) / 256, 256, 0, stream>>>(edge_in + E_in, E_in, deg_in);

    prefix_scan_simple<<<1, 256, 0, stream>>>(deg_nn, rs_nn, N_NODES);
    prefix_scan_simple<<<1, 256, 0, stream>>>(deg_in, rs_in, N_NODES);

    scatter_edges<<<(E_nn + 255) / 256, 256, 0, stream>>>(edge_nn, edge_nn + E_nn, E_nn, rs_nn, fill_nn, sort_nn);
    scatter_edges<<<(E_in + 255) / 256, 256, 0, stream>>>(edge_in, edge_in + E_in, E_in, rs_in, fill_in, sort_in);

    aggregate<<<N_NODES, 128, 0, stream>>>(h_news, asrc_nn, adst_nn, rs_nn, sort_nn, out_nn);
    aggregate<<<N_NODES, 128, 0, stream>>>(h_inter, asrc_in, adst_in, rs_in, sort_in, out_in);

    score_mfma<<<dim3((N_NODES + 127) / 128, 2), 256, 0, stream>>>(out_nn, out_in, wkT, cp, Ssum);
    beta_kernel<<<1, 64, 0, stream>>>(Ssum, cp, beta);

    final_out<<<N_NODES, 128, 0, stream>>>(out_nn, out_in, beta, cp, d_out, flag);
}

// Round 5
// 705.521 us; speedup vs baseline: 1.5256x; 1.2392x over previous
//
#include <hip/hip_runtime.h>
#include <hip/hip_bf16.h>

// ---------------- constants ----------------
#define N_NODES   30000
#define F_IN      768
#define HID       128
#define NHEAD     8
#define C_OUT     4

typedef short short8_t __attribute__((ext_vector_type(8)));
typedef float float4_t __attribute__((ext_vector_type(4)));

__device__ __forceinline__ float b2f(short u) {
    union { unsigned int i; float f; } v;
    v.i = ((unsigned int)(unsigned short)u) << 16;
    return v.f;
}
__device__ __forceinline__ short f2s(float f) {
    __hip_bfloat16 h = __float2bfloat16(f);
    short s; __builtin_memcpy(&s, &h, 2); return s;
}

// ---------------- workspace layout (bytes); total ~41.6 MB ----------------
#define OFF_H_NEWS      0UL          // 30000*128 bf16
#define OFF_H_INTER     7680000UL    // 30000*128 bf16 (only first 30000 inter rows used)
#define OFF_OUT_NN      15360000UL   // 30000*128 bf16
#define OFF_OUT_IN      23040000UL   // 30000*128 bf16
#define OFF_ASRC_NN     30720000UL   // 30000*8 f32
#define OFF_ADST_NN     31680000UL
#define OFF_ASRC_IN     32640000UL
#define OFF_ADST_IN     33600000UL
#define OFF_WT_NEWS     34560000UL   // 128*768 bf16
#define OFF_WT_INTER    34756608UL
#define OFF_RS_NN       34953216UL   // 30001 int (padded)
#define OFF_RS_IN       35073280UL
#define OFF_SORT_NN     35193344UL   // 480000 int
#define OFF_SORT_IN     37113344UL   // 960000 int
#define OFF_ZERO        40953344UL   // start of zeroed region
#define OFF_DEG_NN      40953344UL
#define OFF_FILL_NN     41073408UL
#define OFF_DEG_IN      41193472UL
#define OFF_FILL_IN     41313536UL
#define OFF_SSUM        41433600UL   // 2*128 f32
#define ZERO_BYTES      481280UL     // (OFF_SSUM+1024) - OFF_ZERO
#define OFF_BETA        41434624UL   // 2 f32 (fully written by kernel)
#define OFF_FLAG        41434632UL   // 1 int (written by detect_dtype)
#define OFF_CPAR        41434640UL   // canonical bf16 small params
#define OFF_WKT         41470496UL   // 128*128 bf16, Wk transposed (j-major)

// canonical param block element offsets
#define CP_B_NEWS  0
#define CP_B_INTER 128
#define CP_ASRC_NN 256
#define CP_ADST_NN 384
#define CP_ASRC_IN 512
#define CP_ADST_IN 640
#define CP_WK      768
#define CP_BK      17152
#define CP_Q       17280
#define CP_WOUT    17408
#define CP_BOUT    17920
#define CP_TOTAL   17924

// ---------------- dtype detector ----------------
__global__ void detect_dtype(const unsigned int* __restrict__ x, int* __restrict__ flag) {
    __shared__ int cnt_s;
    if (threadIdx.x == 0) cnt_s = 0;
    __syncthreads();
    int sane = 0;
    for (int i = threadIdx.x; i < 16384; i += 256) {
        unsigned int lo = x[i] & 0xFFFFu;
        unsigned int ex = (lo >> 7) & 0xFFu;       // bf16 exponent field
        if ((ex >= 107u && ex <= 147u) || lo == 0u || lo == 0x8000u) sane++;
    }
    atomicAdd(&cnt_s, sane);
    __syncthreads();
    if (threadIdx.x == 0) *flag = (cnt_s > 8192) ? 1 : 0;   // 1 = bf16, 0 = fp32
}

// ---------------- canonicalize small params to bf16 ----------------
struct SmallParams {
    const void* src[11];
    int n[11];
    int dstoff[11];
};
__global__ void convert_small(SmallParams sp, short* __restrict__ dst,
                              const int* __restrict__ flag) {
    bool isbf = (*flag != 0);
    int idx = blockIdx.x * 256 + threadIdx.x;
    for (int s = 0; s < 11; ++s) {
        if (idx < sp.n[s]) {
            short v = isbf ? ((const short*)sp.src[s])[idx]
                           : f2s(((const float*)sp.src[s])[idx]);
            dst[sp.dstoff[s] + idx] = v;
            return;
        }
        idx -= sp.n[s];
    }
}

// ---------------- W transpose+convert (both weights): [768][128] -> [128][768] bf16 ----------------
__global__ void transpose_w2(const void* __restrict__ Wn, const void* __restrict__ Wi,
                             short* __restrict__ WtN, short* __restrict__ WtI,
                             const int* __restrict__ flag) {
    bool isbf = (*flag != 0);
    const void* Wraw = blockIdx.y ? Wi : Wn;
    short* Wt        = blockIdx.y ? WtI : WtN;
    int idx = blockIdx.x * 256 + threadIdx.x;
    if (idx < F_IN * HID) {
        int n = idx / F_IN;
        int k = idx - n * F_IN;
        short v = isbf ? ((const short*)Wraw)[k * HID + n]
                       : f2s(((const float*)Wraw)[k * HID + n]);
        Wt[idx] = v;
    }
}

// ---------------- Wk transpose (canonical bf16 -> wkT[j][k]) ----------------
__global__ void transpose_wk(const short* __restrict__ cp, short* __restrict__ wkT) {
    int idx = blockIdx.x * 256 + threadIdx.x;
    if (idx < HID * HID) {
        int j = idx >> 7;
        int k = idx & 127;
        wkT[idx] = cp[CP_WK + k * HID + j];
    }
}

// ---------------- projection GEMM (both types): H[m,:] = X[m,:768] @ W + b ----------------
// BM=64 (469 blocks/type for occupancy), BN=128, BK=32; 4 waves x 16 rows.
#define BK   32
#define LDK  40   // padded LDS leading dim

__global__ __launch_bounds__(256) void proj_gemm2(
    const void* __restrict__ Xn, const void* __restrict__ Xi,
    const short* __restrict__ WtN, const short* __restrict__ WtI,
    const short* __restrict__ cp,
    short* __restrict__ Hn, short* __restrict__ Hi,
    int M, const int* __restrict__ flag)
{
    __shared__ __align__(16) short As[64 * LDK];
    __shared__ __align__(16) short Bs[128 * LDK];

    const bool isbf = (*flag != 0);
    const void* Xraw = blockIdx.y ? Xi : Xn;
    const short* Wt  = blockIdx.y ? WtI : WtN;
    const short* bias = cp + (blockIdx.y ? CP_B_INTER : CP_B_NEWS);
    short* Hout      = blockIdx.y ? Hi : Hn;

    int m0   = blockIdx.x * 64;
    int tid  = threadIdx.x;
    int lane = tid & 63;
    int wid  = tid >> 6;
    int quad = lane >> 4;
    int lm   = lane & 15;

    float4_t acc[8];
    #pragma unroll
    for (int c = 0; c < 8; ++c) acc[c] = (float4_t){0.f, 0.f, 0.f, 0.f};

    int sr  = tid >> 2;        // 0..63
    int skp = (tid & 3) * 8;   // 0,8,16,24

    for (int k0 = 0; k0 < F_IN; k0 += BK) {
        __syncthreads();
        {   // A tile: 64 rows x 32 k
            int gm = m0 + sr; if (gm >= M) gm = M - 1;   // clamp (stores guarded later)
            short8_t av;
            if (isbf) {
                av = *(const short8_t*)((const short*)Xraw + (size_t)gm * F_IN + k0 + skp);
            } else {
                const float* xf = (const float*)Xraw + (size_t)gm * F_IN + k0 + skp;
                float4_t f0 = *(const float4_t*)xf;
                float4_t f1 = *(const float4_t*)(xf + 4);
                av[0] = f2s(f0[0]); av[1] = f2s(f0[1]); av[2] = f2s(f0[2]); av[3] = f2s(f0[3]);
                av[4] = f2s(f1[0]); av[5] = f2s(f1[1]); av[6] = f2s(f1[2]); av[7] = f2s(f1[3]);
            }
            *(short8_t*)(&As[sr * LDK + skp]) = av;
        }
        #pragma unroll
        for (int rep = 0; rep < 2; ++rep) {   // B tile: 128 rows x 32 k
            int r = sr + rep * 64;
            short8_t bv = *(const short8_t*)(Wt + (size_t)r * F_IN + k0 + skp);
            *(short8_t*)(&Bs[r * LDK + skp]) = bv;
        }
        __syncthreads();

        short8_t bfrag[8];
        #pragma unroll
        for (int c = 0; c < 8; ++c)
            bfrag[c] = *(const short8_t*)(&Bs[(c * 16 + lm) * LDK + quad * 8]);
        short8_t afrag = *(const short8_t*)(&As[(wid * 16 + lm) * LDK + quad * 8]);
        #pragma unroll
        for (int c = 0; c < 8; ++c)
            acc[c] = __builtin_amdgcn_mfma_f32_16x16x32_bf16(afrag, bfrag[c], acc[c], 0, 0, 0);
    }

    // epilogue: C/D layout col=lane&15, row=(lane>>4)*4+reg
    #pragma unroll
    for (int c = 0; c < 8; ++c)
        #pragma unroll
        for (int r = 0; r < 4; ++r) {
            int row = wid * 16 + quad * 4 + r;
            int gm = m0 + row;
            if (gm < M) {
                int col = c * 16 + lm;
                Hout[(size_t)gm * HID + col] = f2s(acc[c][r] + b2f(bias[col]));
            }
        }
}

// ---------------- per-head attention dots ----------------
__global__ __launch_bounds__(128) void head_dots(
    const short* __restrict__ Hnews, const short* __restrict__ Hinter,
    const short* __restrict__ cp,
    float* __restrict__ asrc_nn, float* __restrict__ adst_nn,
    float* __restrict__ asrc_in, float* __restrict__ adst_in)
{
    int n = blockIdx.x, tid = threadIdx.x;
    int h = tid >> 4, d = tid & 15;
    float hv  = b2f(Hnews[(size_t)n * HID + tid]);
    float hv2 = b2f(Hinter[(size_t)n * HID + tid]);
    float v0 = hv  * b2f(cp[CP_ASRC_NN + tid]);
    float v1 = hv  * b2f(cp[CP_ADST_NN + tid]);
    float v2 = hv2 * b2f(cp[CP_ASRC_IN + tid]);
    float v3 = hv  * b2f(cp[CP_ADST_IN + tid]);
    #pragma unroll
    for (int off = 8; off; off >>= 1) {
        v0 += __shfl_down(v0, off, 16);
        v1 += __shfl_down(v1, off, 16);
        v2 += __shfl_down(v2, off, 16);
        v3 += __shfl_down(v3, off, 16);
    }
    if (d == 0) {
        asrc_nn[n * NHEAD + h] = v0;
        adst_nn[n * NHEAD + h] = v1;
        asrc_in[n * NHEAD + h] = v2;
        adst_in[n * NHEAD + h] = v3;
    }
}

// ---------------- CSR build (both edge types fused) ----------------
__global__ void count_deg2(const int* __restrict__ dnn, int Enn,
                           const int* __restrict__ din, int Ein,
                           int* __restrict__ deg_nn, int* __restrict__ deg_in) {
    int i = blockIdx.x * 256 + threadIdx.x;
    if (i < Enn) {
        int d = dnn[i];
        if (d >= 0 && d < N_NODES) atomicAdd(&deg_nn[d], 1);
    } else {
        int j = i - Enn;
        if (j < Ein) {
            int d = din[j];
            if (d >= 0 && d < N_NODES) atomicAdd(&deg_in[d], 1);
        }
    }
}

__global__ __launch_bounds__(256) void prefix_scan2(
    const int* __restrict__ deg_nn, int* __restrict__ rs_nn,
    const int* __restrict__ deg_in, int* __restrict__ rs_in, int n)
{
    const int* deg = blockIdx.x ? deg_in : deg_nn;
    int* row_start = blockIdx.x ? rs_in : rs_nn;
    __shared__ int psum[256];
    int tid = threadIdx.x;
    int chunk = (n + 255) / 256;
    int lo = tid * chunk;
    int hi = lo + chunk; if (hi > n) hi = n; if (lo > n) lo = n;
    int s = 0;
    for (int i = lo; i < hi; ++i) s += deg[i];
    psum[tid] = s;
    __syncthreads();
    for (int off = 1; off < 256; off <<= 1) {
        int v = (tid >= off) ? psum[tid - off] : 0;
        __syncthreads();
        psum[tid] += v;
        __syncthreads();
    }
    int base = tid ? psum[tid - 1] : 0;   // exclusive prefix of this chunk
    for (int i = lo; i < hi; ++i) { row_start[i] = base; base += deg[i]; }
    if (tid == 255) row_start[n] = psum[255];
}

__global__ void scatter_edges2(const int* __restrict__ enn, int Enn,
                               const int* __restrict__ ein, int Ein,
                               const int* __restrict__ rs_nn, int* __restrict__ fill_nn,
                               int* __restrict__ sort_nn,
                               const int* __restrict__ rs_in, int* __restrict__ fill_in,
                               int* __restrict__ sort_in) {
    int i = blockIdx.x * 256 + threadIdx.x;
    if (i < Enn) {
        int d = enn[Enn + i];
        if (d >= 0 && d < N_NODES) {
            int pos = rs_nn[d] + atomicAdd(&fill_nn[d], 1);
            if (pos >= 0 && pos < Enn) sort_nn[pos] = enn[i];
        }
    } else {
        int j = i - Enn;
        if (j < Ein) {
            int d = ein[Ein + j];
            if (d >= 0 && d < N_NODES) {
                int pos = rs_in[d] + atomicAdd(&fill_in[d], 1);
                if (pos >= 0 && pos < Ein) sort_in[pos] = ein[j];
            }
        }
    }
}

// ---------------- fused edge-softmax + aggregation, wave-per-node ----------------
// 64 lanes/node; lane owns cols (2*lane, 2*lane+1) via one packed uint load.
// Edge indices batch-loaded 64-wide, broadcast via __shfl (no LDS, no barrier).
__global__ __launch_bounds__(256) void aggregate2(
    const short* __restrict__ Hnn, const short* __restrict__ Hin,
    const float* __restrict__ asrc_nn, const float* __restrict__ adst_nn,
    const float* __restrict__ asrc_in, const float* __restrict__ adst_in,
    const int* __restrict__ rs_nn, const int* __restrict__ rs_in,
    const int* __restrict__ sort_nn, const int* __restrict__ sort_in,
    short* __restrict__ out_nn, short* __restrict__ out_in)
{
    int tid = threadIdx.x, w = tid >> 6, lane = tid & 63;
    int type = blockIdx.y;
    const short* H    = type ? Hin : Hnn;
    const float* asrc = type ? asrc_in : asrc_nn;
    const float* adst = type ? adst_in : adst_nn;
    const int*   rs   = type ? rs_in : rs_nn;
    const int*   ss   = type ? sort_in : sort_nn;
    short* outb       = type ? out_in : out_nn;

    int dn = blockIdx.x * 4 + w;                  // 7500*4 == 30000 exactly
    int start = rs[dn], end = rs[dn + 1];
    int head = lane >> 3;                         // cols (2l,2l+1) share head
    float adv = adst[dn * NHEAD + head];

    float den = 0.f, a0 = 0.f, a1 = 0.f;
    for (int base = start; base < end; base += 64) {
        int nb = end - base; if (nb > 64) nb = 64;
        int myidx = 0;
        if (base + lane < end) myidx = ss[base + lane];
        for (int j = 0; j < nb; ++j) {
            int s = __shfl(myidx, j, 64);
            s = (s < 0) ? 0 : (s >= N_NODES ? N_NODES - 1 : s);   // containment
            float e = asrc[s * NHEAD + head] + adv;
            e = fmaxf(e, 0.2f * e);               // leaky_relu, slope 0.2
            e = fminf(e, 80.f);
            float ex = __expf(e);
            unsigned int hv = *(const unsigned int*)(H + (size_t)s * HID + lane * 2);
            den += ex;
            a0 += ex * b2f((short)(hv & 0xFFFFu));
            a1 += ex * b2f((short)(hv >> 16));
        }
    }
    float inv = 1.f / (den + 1e-16f);
    unsigned int lo16 = (unsigned short)f2s(fmaxf(a0 * inv, 0.f));
    unsigned int hi16 = (unsigned short)f2s(fmaxf(a1 * inv, 0.f));
    *(unsigned int*)(outb + (size_t)dn * HID + lane * 2) = lo16 | (hi16 << 16);
}

// ---------------- semantic score via MFMA ----------------
__global__ __launch_bounds__(256) void score_mfma(
    const short* __restrict__ out_nn, const short* __restrict__ out_in,
    const short* __restrict__ wkT, const short* __restrict__ cp,
    float* __restrict__ Ssum)
{
    __shared__ float col_s[HID];
    int tid  = threadIdx.x;
    int lane = tid & 63;
    int wid  = tid >> 6;
    int quad = lane >> 4;
    int lm   = lane & 15;
    const short* src = blockIdx.y ? out_in : out_nn;
    int m0 = blockIdx.x * 128;

    if (tid < HID) col_s[tid] = 0.f;
    __syncthreads();

    float4_t acc[2][8];
    #pragma unroll
    for (int i = 0; i < 2; ++i)
        #pragma unroll
        for (int c = 0; c < 8; ++c)
            acc[i][c] = (float4_t){0.f, 0.f, 0.f, 0.f};

    #pragma unroll
    for (int kc = 0; kc < 4; ++kc) {
        short8_t bfrag[8];
        #pragma unroll
        for (int c = 0; c < 8; ++c)
            bfrag[c] = *(const short8_t*)(wkT + (c * 16 + lm) * HID + kc * 32 + quad * 8);
        #pragma unroll
        for (int i = 0; i < 2; ++i) {
            int gm = m0 + wid * 32 + i * 16 + lm;
            if (gm >= N_NODES) gm = N_NODES - 1;      // clamp; epilogue guards
            short8_t afrag = *(const short8_t*)(src + (size_t)gm * HID + kc * 32 + quad * 8);
            #pragma unroll
            for (int c = 0; c < 8; ++c)
                acc[i][c] = __builtin_amdgcn_mfma_f32_16x16x32_bf16(afrag, bfrag[c], acc[i][c], 0, 0, 0);
        }
    }

    // epilogue: tanh + row-sum.  C/D layout: col=c*16+lm, row=wid*32+i*16+quad*4+r
    #pragma unroll
    for (int c = 0; c < 8; ++c) {
        int col = c * 16 + lm;
        float bkc = b2f(cp[CP_BK + col]);
        float lsum = 0.f;
        #pragma unroll
        for (int i = 0; i < 2; ++i)
            #pragma unroll
            for (int r = 0; r < 4; ++r) {
                int node = m0 + wid * 32 + i * 16 + quad * 4 + r;
                if (node < N_NODES) {
                    float a = acc[i][c][r] + bkc;
                    a = fminf(fmaxf(a, -15.f), 15.f);
                    float t = __expf(2.f * a);
                    lsum += (t - 1.f) / (t + 1.f);
                }
            }
        float v = lsum;
        v += __shfl_down(v, 32, 64);
        v += __shfl_down(v, 16, 64);
        if (quad == 0) atomicAdd(&col_s[col], v);
    }
    __syncthreads();
    if (tid < HID) atomicAdd(&Ssum[blockIdx.y * HID + tid], col_s[tid]);
}

// ---------------- beta (softmax over 2 metapath scores) ----------------
__global__ __launch_bounds__(64) void beta_kernel(
    const float* __restrict__ Ssum, const short* __restrict__ cp, float* __restrict__ beta)
{
    int lane = threadIdx.x;
    float q0 = b2f(cp[CP_Q + lane]), q1 = b2f(cp[CP_Q + lane + 64]);
    float s0 = q0 * Ssum[lane] + q1 * Ssum[lane + 64];
    float s1 = q0 * Ssum[128 + lane] + q1 * Ssum[192 + lane];
    #pragma unroll
    for (int off = 32; off; off >>= 1) {
        s0 += __shfl_down(s0, off, 64);
        s1 += __shfl_down(s1, off, 64);
    }
    if (lane == 0) {
        float sc0 = s0 / (float)N_NODES;
        float sc1 = s1 / (float)N_NODES;
        float mx = fmaxf(sc0, sc1);
        float e0 = __expf(sc0 - mx), e1 = __expf(sc1 - mx);
        float inv = 1.f / (e0 + e1);
        beta[0] = e0 * inv;
        beta[1] = e1 * inv;
    }
}

// ---------------- final: elu(beta0*out_nn + beta1*out_in) @ W_out + b_out ----------------
__global__ __launch_bounds__(128) void final_out(
    const short* __restrict__ out_nn, const short* __restrict__ out_in,
    const float* __restrict__ beta, const short* __restrict__ cp,
    void* __restrict__ Yraw, const int* __restrict__ flag)
{
    __shared__ float partial[2][C_OUT];
    bool isbf = (*flag != 0);
    int n = blockIdx.x, tid = threadIdx.x, lane = tid & 63, w = tid >> 6;
    float b0 = beta[0], b1 = beta[1];
    float f = b0 * b2f(out_nn[(size_t)n * HID + tid]) + b1 * b2f(out_in[(size_t)n * HID + tid]);
    float e = (f > 0.f) ? f : expm1f(f);
    float p[C_OUT];
    #pragma unroll
    for (int c = 0; c < C_OUT; ++c) p[c] = e * b2f(cp[CP_WOUT + tid * C_OUT + c]);
    #pragma unroll
    for (int off = 32; off; off >>= 1)
        #pragma unroll
        for (int c = 0; c < C_OUT; ++c) p[c] += __shfl_down(p[c], off, 64);
    if (lane == 0)
        #pragma unroll
        for (int c = 0; c < C_OUT; ++c) partial[w][c] = p[c];
    __syncthreads();
    if (tid < C_OUT) {
        float r = partial[0][tid] + partial[1][tid] + b2f(cp[CP_BOUT + tid]);
        if (isbf) ((__hip_bfloat16*)Yraw)[n * C_OUT + tid] = __float2bfloat16(r);
        else      ((float*)Yraw)[n * C_OUT + tid] = r;
    }
}

// ---------------- launch ----------------
extern "C" void kernel_launch(void* const* d_in, const int* in_sizes, int n_in,
                              void* d_out, int out_size, void* d_ws, size_t ws_size,
                              hipStream_t stream) {
    const void* x_news  = d_in[0];
    const void* x_inter = d_in[1];
    const int*  edge_nn = (const int*)d_in[2];
    const int*  edge_in = (const int*)d_in[3];

    int E_nn = in_sizes[2] / 2;
    int E_in = in_sizes[3] / 2;

    char* ws = (char*)d_ws;
    short* h_news  = (short*)(ws + OFF_H_NEWS);
    short* h_inter = (short*)(ws + OFF_H_INTER);
    short* out_nn  = (short*)(ws + OFF_OUT_NN);
    short* out_in  = (short*)(ws + OFF_OUT_IN);
    float* asrc_nn = (float*)(ws + OFF_ASRC_NN);
    float* adst_nn = (float*)(ws + OFF_ADST_NN);
    float* asrc_in = (float*)(ws + OFF_ASRC_IN);
    float* adst_in = (float*)(ws + OFF_ADST_IN);
    short* wt_news  = (short*)(ws + OFF_WT_NEWS);
    short* wt_inter = (short*)(ws + OFF_WT_INTER);
    int* rs_nn   = (int*)(ws + OFF_RS_NN);
    int* rs_in   = (int*)(ws + OFF_RS_IN);
    int* sort_nn = (int*)(ws + OFF_SORT_NN);
    int* sort_in = (int*)(ws + OFF_SORT_IN);
    int* deg_nn  = (int*)(ws + OFF_DEG_NN);
    int* fill_nn = (int*)(ws + OFF_FILL_NN);
    int* deg_in  = (int*)(ws + OFF_DEG_IN);
    int* fill_in = (int*)(ws + OFF_FILL_IN);
    float* Ssum  = (float*)(ws + OFF_SSUM);
    float* beta  = (float*)(ws + OFF_BETA);
    int*   flag  = (int*)(ws + OFF_FLAG);
    short* cp    = (short*)(ws + OFF_CPAR);
    short* wkT   = (short*)(ws + OFF_WKT);

    hipMemsetAsync(ws + OFF_ZERO, 0, ZERO_BYTES, stream);

    detect_dtype<<<1, 256, 0, stream>>>((const unsigned int*)x_news, flag);

    SmallParams sp;
    const int srcidx[11] = {5, 7, 8, 9, 10, 11, 12, 13, 14, 15, 16};
    const int ns[11]     = {128, 128, 128, 128, 128, 128, 16384, 128, 128, 512, 4};
    const int doff[11]   = {CP_B_NEWS, CP_B_INTER, CP_ASRC_NN, CP_ADST_NN, CP_ASRC_IN,
                            CP_ADST_IN, CP_WK, CP_BK, CP_Q, CP_WOUT, CP_BOUT};
    for (int i = 0; i < 11; ++i) { sp.src[i] = d_in[srcidx[i]]; sp.n[i] = ns[i]; sp.dstoff[i] = doff[i]; }
    convert_small<<<(CP_TOTAL + 255) / 256, 256, 0, stream>>>(sp, cp, flag);

    transpose_wk<<<(HID * HID + 255) / 256, 256, 0, stream>>>(cp, wkT);

    transpose_w2<<<dim3((F_IN * HID + 255) / 256, 2), 256, 0, stream>>>(
        d_in[4], d_in[6], wt_news, wt_inter, flag);

    proj_gemm2<<<dim3((N_NODES + 63) / 64, 2), 256, 0, stream>>>(
        x_news, x_inter, wt_news, wt_inter, cp, h_news, h_inter, N_NODES, flag);

    head_dots<<<N_NODES, 128, 0, stream>>>(h_news, h_inter, cp,
        asrc_nn, adst_nn, asrc_in, adst_in);

    count_deg2<<<(E_nn + E_in + 255) / 256, 256, 0, stream>>>(
        edge_nn + E_nn, E_nn, edge_in + E_in, E_in, deg_nn, deg_in);

    prefix_scan2<<<2, 256, 0, stream>>>(deg_nn, rs_nn, deg_in, rs_in, N_NODES);

    scatter_edges2<<<(E_nn + E_in + 255) / 256, 256, 0, stream>>>(
        edge_nn, E_nn, edge_in, E_in, rs_nn, fill_nn, sort_nn, rs_in, fill_in, sort_in);

    aggregate2<<<dim3(N_NODES / 4, 2), 256, 0, stream>>>(
        h_news, h_inter, asrc_nn, adst_nn, asrc_in, adst_in,
        rs_nn, rs_in, sort_nn, sort_in, out_nn, out_in);

    score_mfma<<<dim3((N_NODES + 127) / 128, 2), 256, 0, stream>>>(out_nn, out_in, wkT, cp, Ssum);
    beta_kernel<<<1, 64, 0, stream>>>(Ssum, cp, beta);

    final_out<<<N_NODES, 128, 0, stream>>>(out_nn, out_in, beta, cp, d_out, flag);
}